// Round 13
// baseline (20.217 us; speedup 1.0000x reference)
//
#include <hip/hip_runtime.h>
#include <math.h>

// ---------------------------------------------------------------------------
// WeightedRandomSampler (inverse-CDF multinomial), 2-kernel design (= round-8
// structure, SPT 4->2 for full occupancy):
//   K1 gsum_kernel  : coalesced float4 read of freq; 4-lane shfl reduce ->
//                     group sums gsum[G] in ws (G = ceil(V/16) = 3142).
//   K2 sample_kernel: per block: 7 gsum loads/thread -> block scan -> padded
//                     group-CDF in LDS (phys(i) = i + i/32 de-conflicts the
//                     pow2-stride bsearch). Per sample: 12-level branchless
//                     LDS bsearch -> group g; 4x float4 freq reload (L2-hot)
//                     prefix + compare-count -> searchsorted 'right'; clip.
//   Round-12 change (ONLY): SPT 4->2 => 1024 blocks, 4 blocks/CU, 32 waves/CU
//   (full cap; r6 ran 2 waves/SIMD, r8 4 waves/SIMD). Mechanism: the ~6us of
//   kernel time is dependent-LDS-probe latency; double the resident waves to
//   hide it. LDS 16.9KB x 4 blocks = 68KB << 160KB; VGPR ~52 -> not limiting.
// ---------------------------------------------------------------------------

#define GRP 16        // freq elements per group
#define TPB 512       // sampler threads per block (8 waves)
#define SPT 2         // samples per thread -> 1024 blocks, 4 blocks/CU
#define GPT_MAX 16    // max groups per thread (supports G <= 8192)

__device__ __forceinline__ int physIdx(int i) { return i + (i >> 5); }

__global__ __launch_bounds__(256) void gsum_kernel(const float* __restrict__ freq,
                                                   int V, float* __restrict__ gsum) {
    const int i4 = blockIdx.x * 256 + threadIdx.x;   // float4 index
    const int nf4 = (V + 3) >> 2;
    float s = 0.f;
    if (i4 < nf4) {
        const int base = i4 * 4;
        if (base + 3 < V) {
            const float4 v = *reinterpret_cast<const float4*>(freq + base);
            s = v.x + v.y + v.z + v.w;
        } else {
            for (int j = 0; j < 4; ++j)
                if (base + j < V) s += freq[base + j];
        }
    }
    // 4 consecutive lanes (aligned quads) hold one 16-elem group
    s += __shfl_xor(s, 1);
    s += __shfl_xor(s, 2);
    const int g = i4 >> 2;
    const int G = (V + GRP - 1) / GRP;
    if ((threadIdx.x & 3) == 0 && g < G) gsum[g] = s;
}

template <int PAD>
__global__ __launch_bounds__(TPB) void sample_kernel(const float* __restrict__ freq,
                                                     const float* __restrict__ u,
                                                     const float* __restrict__ gsum,
                                                     float* __restrict__ out,
                                                     int N, int V, int G) {
    __shared__ float sS[PAD + (PAD >> 5)];   // padded group-CDF
    __shared__ float wsum[TPB / 64];
    const int t = threadIdx.x;
    const int lane = t & 63;
    const int w = t >> 6;
    const int GPT = (G + TPB - 1) / TPB;     // 7 for G=3142

    // hoisted sample load: issue the HBM read before the scan so its latency
    // hides under phase A (cannot be hoisted past __syncthreads by hipcc)
    const int gid = blockIdx.x * TPB + t;
    const long long i0 = (long long)gid * SPT;
    float uk[SPT];
    const bool full = (i0 + SPT <= N);
    if (full) {
        const float2 A = *reinterpret_cast<const float2*>(u + i0);
        uk[0] = A.x; uk[1] = A.y;
    } else {
#pragma unroll
        for (int s = 0; s < SPT; ++s) uk[s] = (i0 + s < N) ? u[i0 + s] : 0.f;
    }

    // ---- phase A: block scan of group sums ----
    const int g0 = t * GPT;
    float ls[GPT_MAX];                       // compile-time indexed
    float runv = 0.f;
#pragma unroll
    for (int k = 0; k < GPT_MAX; ++k) {
        float s = 0.f;
        if (k < GPT) { const int g = g0 + k; if (g < G) s = gsum[g]; }
        runv += s;
        ls[k] = runv;
    }
    float sc = runv;                         // wave-inclusive scan of totals
#pragma unroll
    for (int off = 1; off <= 32; off <<= 1) {
        const float v = __shfl_up(sc, off);
        if (lane >= off) sc += v;
    }
    if (lane == 63) wsum[w] = sc;
    __syncthreads();
    float tbase = sc - runv;                 // exclusive base for this thread
    for (int k = 0; k < w; ++k) tbase += wsum[k];

#pragma unroll
    for (int k = 0; k < GPT_MAX; ++k) {
        if (k < GPT) { const int g = g0 + k; if (g < G) sS[physIdx(g)] = tbase + ls[k]; }
    }
    for (int i = G + t; i < PAD; i += TPB) sS[physIdx(i)] = INFINITY;  // pads
    __syncthreads();

    if (i0 >= N) return;                     // after all barriers

    const float total = sS[physIdx(G - 1)];  // broadcast LDS read

    // ---- phase B: sample ----
    float ok[SPT];
#pragma unroll
    for (int s = 0; s < SPT; ++s) {
        const float key = uk[s] * total;

        // branchless "count of entries <= key" over PAD sorted values
        int pos = -1;
#pragma unroll
        for (int step = PAD >> 1; step >= 1; step >>= 1) {
            const int j = pos + step;
            pos += (sS[physIdx(j)] <= key) ? step : 0;
        }
        int g = pos + 1;                     // group holding the boundary
        g = (g > G - 1) ? (G - 1) : g;
        const float base = (g > 0) ? sS[physIdx(g - 1)] : 0.f;
        const int eb = g * GRP;

        float r = base;
        int cnt = 0;
        if (eb + GRP <= V) {
            const float4* fp = reinterpret_cast<const float4*>(freq + eb);
            const float4 a = fp[0], b = fp[1], c = fp[2], d = fp[3];
            r += a.x; cnt += (r <= key); r += a.y; cnt += (r <= key);
            r += a.z; cnt += (r <= key); r += a.w; cnt += (r <= key);
            r += b.x; cnt += (r <= key); r += b.y; cnt += (r <= key);
            r += b.z; cnt += (r <= key); r += b.w; cnt += (r <= key);
            r += c.x; cnt += (r <= key); r += c.y; cnt += (r <= key);
            r += c.z; cnt += (r <= key); r += c.w; cnt += (r <= key);
            r += d.x; cnt += (r <= key); r += d.y; cnt += (r <= key);
            r += d.z; cnt += (r <= key); r += d.w; cnt += (r <= key);
        } else {                             // tail group, guarded
            for (int j = 0; j < GRP; ++j) {
                const int idx = eb + j;
                if (idx < V) { r += freq[idx]; cnt += (r <= key); }
            }
        }
        int ans = eb + cnt;                  // searchsorted 'right'
        ans = (ans > V - 1) ? (V - 1) : ans; // clip like reference
        ok[s] = (float)ans;
    }

    if (full) {
        *reinterpret_cast<float2*>(out + i0) = make_float2(ok[0], ok[1]);
    } else {
        for (int s = 0; s < SPT; ++s)
            if (i0 + s < N) out[i0 + s] = ok[s];
    }
}

extern "C" void kernel_launch(void* const* d_in, const int* in_sizes, int n_in,
                              void* d_out, int out_size, void* d_ws, size_t ws_size,
                              hipStream_t stream) {
    const float* freq = (const float*)d_in[0];
    const float* u    = (const float*)d_in[1];
    float* out        = (float*)d_out;
    const int V = in_sizes[0];
    const int N = in_sizes[1];
    const int G = (V + GRP - 1) / GRP;                 // 3142 for V=50257

    float* gsum = (float*)d_ws;                        // G floats in ws

    const int nf4 = (V + 3) >> 2;
    hipLaunchKernelGGL(gsum_kernel, dim3((nf4 + 255) / 256), dim3(256), 0, stream,
                       freq, V, gsum);

    const int NB = (N + TPB * SPT - 1) / (TPB * SPT);  // 1024 for N=2^20
    if (G < 1024) {
        hipLaunchKernelGGL(sample_kernel<1024>, dim3(NB), dim3(TPB), 0, stream,
                           freq, u, gsum, out, N, V, G);
    } else if (G < 2048) {
        hipLaunchKernelGGL(sample_kernel<2048>, dim3(NB), dim3(TPB), 0, stream,
                           freq, u, gsum, out, N, V, G);
    } else if (G < 4096) {
        hipLaunchKernelGGL(sample_kernel<4096>, dim3(NB), dim3(TPB), 0, stream,
                           freq, u, gsum, out, N, V, G);
    } else {
        hipLaunchKernelGGL(sample_kernel<8192>, dim3(NB), dim3(TPB), 0, stream,
                           freq, u, gsum, out, N, V, G);
    }
}

// Round 14
// 19.377 us; speedup vs baseline: 1.0433x; 1.0433x over previous
//
#include <hip/hip_runtime.h>
#include <math.h>

// ---------------------------------------------------------------------------
// WeightedRandomSampler (inverse-CDF multinomial), SINGLE-KERNEL design
// (round-6 structure, 19.3us — best measured — plus hoisted u-loads):
//   Each block independently (redundantly) builds a group-level CDF in LDS:
//     group g = freq[16g .. 16g+16); cdfS[g] = cdf[16g+15]  (G = ceil(V/16))
//   stored in a bank-de-conflicted padded layout phys(i) = i + i/32
//   (binary-search strides are powers of two -> padding de-conflicts banks).
//   Per sample: key = u*total; 12-level branchless LDS bsearch -> group g;
//   reload that group's 16 freqs (one 64B L2-hot line), sequential prefix +
//   compare-count -> exact searchsorted(cdf, key, 'right'); clip; float out.
//   Round-13 change (ONLY): u float4 loads issued BEFORE phase 1 so the 4MB
//   HBM stream latency overlaps the redundant scan (hipcc cannot hoist loads
//   across __syncthreads).
//   Plateau evidence (r5-r12): all sane designs 19.3-20.2us; occupancy x2,
//   refine/4, probes/4, setup-redundancy-removal all null/negative ->
//   ~13us fixed replay overhead + ~1.3us essential HBM + ~5us search.
// ---------------------------------------------------------------------------

#define TPB 512       // threads per block (8 waves)
#define SPT 8         // samples per thread
#define GRP 16        // freq elements per group
#define GPT_MAX 16    // max groups per thread (supports V <= 131072)

__device__ __forceinline__ int physIdx(int i) { return i + (i >> 5); }

template <int PAD>
__global__ __launch_bounds__(TPB) void sampler_kernel(const float* __restrict__ freq,
                                                      const float* __restrict__ u,
                                                      float* __restrict__ out,
                                                      int N, int V, int G) {
    __shared__ float sS[PAD + (PAD >> 5)];   // padded group-CDF
    __shared__ float wsum[TPB / 64];
    const int t = threadIdx.x;
    const int lane = t & 63;
    const int w = t >> 6;

    // ---- hoisted sample loads: overlap the 4MB u-stream with phase 1 ----
    const int gid = blockIdx.x * TPB + t;
    const long long i0 = (long long)gid * SPT;
    float uk[SPT];
    const bool full = (i0 + SPT <= N);
    if (full) {
        const float4 A = *reinterpret_cast<const float4*>(u + i0);
        const float4 B = *reinterpret_cast<const float4*>(u + i0 + 4);
        uk[0] = A.x; uk[1] = A.y; uk[2] = A.z; uk[3] = A.w;
        uk[4] = B.x; uk[5] = B.y; uk[6] = B.z; uk[7] = B.w;
    } else {
#pragma unroll
        for (int s = 0; s < SPT; ++s) uk[s] = (i0 + s < N) ? u[i0 + s] : 0.f;
    }

    // ---- phase 1: per-block redundant group-sum scan ----
    const int GPT = (G + TPB - 1) / TPB;     // 7 for V=50257
    const int g0 = t * GPT;

    float ls[GPT_MAX];                       // compile-time indexed (unrolled)
    float runv = 0.f;
#pragma unroll
    for (int k = 0; k < GPT_MAX; ++k) {
        float s = 0.f;
        if (k < GPT) {
            const int g = g0 + k;
            if (g < G) {
                const int base = g * GRP;
                if (base + GRP <= V) {
                    const float4* fp = reinterpret_cast<const float4*>(freq + base);
                    const float4 a = fp[0], b = fp[1], c = fp[2], d = fp[3];
                    s = a.x; s += a.y; s += a.z; s += a.w;
                    s += b.x; s += b.y; s += b.z; s += b.w;
                    s += c.x; s += c.y; s += c.z; s += c.w;
                    s += d.x; s += d.y; s += d.z; s += d.w;
                } else {                      // tail group, guarded
                    for (int j = 0; j < GRP; ++j) {
                        const int idx = base + j;
                        if (idx < V) s += freq[idx];
                    }
                }
            }
        }
        runv += s;
        ls[k] = runv;                        // local inclusive scan
    }

    // wave-inclusive scan of thread totals, then cross-wave bases
    float sc = runv;
#pragma unroll
    for (int off = 1; off <= 32; off <<= 1) {
        const float v = __shfl_up(sc, off);
        if (lane >= off) sc += v;
    }
    if (lane == 63) wsum[w] = sc;
    __syncthreads();
    float tbase = sc - runv;                 // exclusive base for this thread
    for (int k = 0; k < w; ++k) tbase += wsum[k];

#pragma unroll
    for (int k = 0; k < GPT_MAX; ++k) {
        if (k < GPT) {
            const int g = g0 + k;
            if (g < G) sS[physIdx(g)] = tbase + ls[k];
        }
    }
    for (int i = G + t; i < PAD; i += TPB) sS[physIdx(i)] = INFINITY;  // pads
    __syncthreads();

    if (i0 >= N) return;                     // after all barriers

    const float total = sS[physIdx(G - 1)];  // broadcast LDS read

    // ---- phase 2: sample ----
    float ok[SPT];
#pragma unroll
    for (int s = 0; s < SPT; ++s) {
        const float key = uk[s] * total;

        // branchless "count of entries <= key" over PAD sorted values
        int pos = -1;
#pragma unroll
        for (int step = PAD >> 1; step >= 1; step >>= 1) {
            const int j = pos + step;        // always in [0, PAD-2]
            pos += (sS[physIdx(j)] <= key) ? step : 0;
        }
        int g = pos + 1;                     // group holding the boundary
        g = (g > G - 1) ? (G - 1) : g;
        const float base = (g > 0) ? sS[physIdx(g - 1)] : 0.f;
        const int eb = g * GRP;

        float r = base;
        int cnt = 0;
        if (eb + GRP <= V) {
            const float4* fp = reinterpret_cast<const float4*>(freq + eb);
            const float4 a = fp[0], b = fp[1], c = fp[2], d = fp[3];
            r += a.x; cnt += (r <= key); r += a.y; cnt += (r <= key);
            r += a.z; cnt += (r <= key); r += a.w; cnt += (r <= key);
            r += b.x; cnt += (r <= key); r += b.y; cnt += (r <= key);
            r += b.z; cnt += (r <= key); r += b.w; cnt += (r <= key);
            r += c.x; cnt += (r <= key); r += c.y; cnt += (r <= key);
            r += c.z; cnt += (r <= key); r += c.w; cnt += (r <= key);
            r += d.x; cnt += (r <= key); r += d.y; cnt += (r <= key);
            r += d.z; cnt += (r <= key); r += d.w; cnt += (r <= key);
        } else {                             // tail group, guarded
            for (int j = 0; j < GRP; ++j) {
                const int idx = eb + j;
                if (idx < V) { r += freq[idx]; cnt += (r <= key); }
            }
        }
        int ans = eb + cnt;                  // searchsorted 'right'
        ans = (ans > V - 1) ? (V - 1) : ans; // clip like reference
        ok[s] = (float)ans;
    }

    if (full) {
        *reinterpret_cast<float4*>(out + i0)     = make_float4(ok[0], ok[1], ok[2], ok[3]);
        *reinterpret_cast<float4*>(out + i0 + 4) = make_float4(ok[4], ok[5], ok[6], ok[7]);
    } else {
        for (int s = 0; s < SPT; ++s)
            if (i0 + s < N) out[i0 + s] = ok[s];
    }
}

extern "C" void kernel_launch(void* const* d_in, const int* in_sizes, int n_in,
                              void* d_out, int out_size, void* d_ws, size_t ws_size,
                              hipStream_t stream) {
    const float* freq = (const float*)d_in[0];
    const float* u    = (const float*)d_in[1];
    float* out        = (float*)d_out;
    const int V = in_sizes[0];
    const int N = in_sizes[1];
    const int G = (V + GRP - 1) / GRP;                 // 3142 for V=50257
    const int NB = (N + TPB * SPT - 1) / (TPB * SPT);  // 256 for N=2^20

    // PAD = smallest pow2 > G (need at least one +INF pad entry)
    if (G < 1024) {
        hipLaunchKernelGGL(sampler_kernel<1024>, dim3(NB), dim3(TPB), 0, stream,
                           freq, u, out, N, V, G);
    } else if (G < 2048) {
        hipLaunchKernelGGL(sampler_kernel<2048>, dim3(NB), dim3(TPB), 0, stream,
                           freq, u, out, N, V, G);
    } else if (G < 4096) {
        hipLaunchKernelGGL(sampler_kernel<4096>, dim3(NB), dim3(TPB), 0, stream,
                           freq, u, out, N, V, G);
    } else {
        hipLaunchKernelGGL(sampler_kernel<8192>, dim3(NB), dim3(TPB), 0, stream,
                           freq, u, out, N, V, G);
    }
}